// Round 1
// baseline (769.308 us; speedup 1.0000x reference)
//
#include <hip/hip_runtime.h>
#include <stdint.h>

#define HID 768
#define NB  128

typedef _Float16 half8    __attribute__((ext_vector_type(8)));
typedef __fp16   fp16x2   __attribute__((ext_vector_type(2)));
typedef float    float4_t __attribute__((ext_vector_type(4)));
typedef float    f32x16   __attribute__((ext_vector_type(16)));

// ws layout: fp16 hi plane [24 i32-tile][48 k16-tile][64 lane][8 halves], then lo plane.
// Lane l of tile (i32,k16) holds op[i32*32 + (l&31)][k16*16 + (l>>5)*8 .. +8]
// == the B-operand fragment of mfma_f32_32x32x16_f16 (col = l&31, k = (l>>5)*8 + r).
#define OP_TILES (24 * 48)
#define OP_PLANE ((size_t)OP_TILES * 64 * 8)   // 1.18 MB per plane

__device__ __forceinline__ void convert8(const float4_t a, const float4_t b,
                                         half8& h, half8& l)
{
    // hi = RTZ pack (1 instr / 2 floats); lo = exact residual, RTZ-packed.
    fp16x2 h01 = __builtin_amdgcn_cvt_pkrtz(a[0], a[1]);
    fp16x2 h23 = __builtin_amdgcn_cvt_pkrtz(a[2], a[3]);
    fp16x2 h45 = __builtin_amdgcn_cvt_pkrtz(b[0], b[1]);
    fp16x2 h67 = __builtin_amdgcn_cvt_pkrtz(b[2], b[3]);
    fp16x2 l01 = __builtin_amdgcn_cvt_pkrtz(a[0] - (float)h01[0], a[1] - (float)h01[1]);
    fp16x2 l23 = __builtin_amdgcn_cvt_pkrtz(a[2] - (float)h23[0], a[3] - (float)h23[1]);
    fp16x2 l45 = __builtin_amdgcn_cvt_pkrtz(b[0] - (float)h45[0], b[1] - (float)h45[1]);
    fp16x2 l67 = __builtin_amdgcn_cvt_pkrtz(b[2] - (float)h67[0], b[3] - (float)h67[1]);
    h = (half8){(_Float16)h01[0], (_Float16)h01[1], (_Float16)h23[0], (_Float16)h23[1],
                (_Float16)h45[0], (_Float16)h45[1], (_Float16)h67[0], (_Float16)h67[1]};
    l = (half8){(_Float16)l01[0], (_Float16)l01[1], (_Float16)l23[0], (_Float16)l23[1],
                (_Float16)l45[0], (_Float16)l45[1], (_Float16)l67[0], (_Float16)l67[1]};
}

// Pre-split operator into fp16 hi/lo in 32x32 B-fragment order.
__global__ __launch_bounds__(256)
void split_op(const float* __restrict__ OP, _Float16* __restrict__ ws)
{
    const int g    = blockIdx.x * 256 + threadIdx.x;
    const int tile = g >> 6, lane = g & 63;
    const int i32t = tile / 48, k16 = tile % 48;
    const int i = i32t * 32 + (lane & 31);
    const int k = k16 * 16 + (lane >> 5) * 8;
    const float4_t a = *(const float4_t*)(OP + (size_t)i * HID + k);
    const float4_t b = *(const float4_t*)(OP + (size_t)i * HID + k + 4);
    half8 h, l;
    convert8(a, b, h, l);
    *(half8*)(ws + (size_t)(tile * 64 + lane) * 8) = h;
    *(half8*)(ws + OP_PLANE + (size_t)(tile * 64 + lane) * 8) = l;
}

// D[b,i] = sum_j op[i,j] * P[j,i],  P = X_b @ op^T (k-reduction).
// Block: (b, 128 i) x 128-j tiles; wave: 64j x 64i as 2x2 of 32x32x16 f16 MFMA.
// X staged RAW fp32 into LDS via global_load_lds (linear dest -> no bank conflicts,
// no VGPR staging), double-buffered, ONE barrier per K-step (T3 2-phase template).
// fp16 hi/lo split happens register-side after the fragment read.
// LDS fp32 layout: slot s (16B) = (rt*2+kh)*128 + hi8*64 + q*32 + m
//   holds X[j0 + rt*32 + m][k0 + kh*16 + hi8*8 + q*4 .. +4]
__global__ __launch_bounds__(256, 3)
void diag_quad_kernel(const float* __restrict__ X, const float* __restrict__ OP,
                      const _Float16* __restrict__ opws, float* __restrict__ out)
{
    __shared__ __align__(16) float Abuf[2][4096];   // 2 x 16 KB (128 rows x 32 k fp32)
    __shared__ float Dred[2][128];

    // XCD swizzle: 6 i-tile blocks of a batch share an XCD (L2 reuse of X_b)
    const int idx  = blockIdx.x;
    const int xcd  = idx & 7, slot = idx >> 3;
    const int b    = xcd * 16 + slot / 6;
    const int it   = slot % 6;
    const int i0   = it * 128;
    const float* Xb = X + (size_t)b * HID * HID;

    const int tid  = threadIdx.x;
    const int lane = tid & 63;
    const int wave = tid >> 6;
    const int wj   = wave & 1;      // j-half (64 rows)
    const int wi   = wave >> 1;     // i-half (64 cols)
    const int l5   = lane >> 5;     // 0/1
    const int m32  = lane & 31;

    // staging: wave w DMAs rows w*32..w*32+31; lane l: row = w*32 + (l&31),
    // issue i covers k columns i*8 + (l>>5)*4  (4 x 16B per lane per step)
    const int srow = wave * 32 + m32;
    const int scol = l5 * 4;

    float p0 = 0.f, p1 = 0.f;

#define STAGE4(bufp, srcbase)                                                          \
    {                                                                                  \
        const float* _s = (srcbase);                                                   \
        _Pragma("unroll")                                                              \
        for (int _i = 0; _i < 4; ++_i)                                                 \
            __builtin_amdgcn_global_load_lds(                                          \
                (const __attribute__((address_space(1))) uint32_t*)(_s + _i * 8),      \
                (__attribute__((address_space(3))) uint32_t*)&(bufp)[(wave * 4 + _i) * 256], \
                16, 0, 0);                                                             \
    }

    // prologue: stage (jt=0, ks=0) into buf 0
    STAGE4(Abuf[0], Xb + (size_t)srow * HID + scol);
    __syncthreads();

    f32x16 acc[2][2];
    int jt = 0, ks = 0;
    for (int t = 0; t < 144; ++t) {
        const int cur = t & 1;
        const int j0  = jt * 128;

        // B fragments straight from ws (L2) — no LDS dependency
        half8 bh[2][2], bl[2][2];
#pragma unroll
        for (int tj = 0; tj < 2; ++tj) {
            const int i32t = it * 4 + wi * 2 + tj;
#pragma unroll
            for (int kh = 0; kh < 2; ++kh) {
                const size_t o = ((size_t)(i32t * 48 + ks * 2 + kh)) * 512 + (size_t)lane * 8;
                bh[tj][kh] = *(const half8*)(opws + o);
                bl[tj][kh] = *(const half8*)(opws + OP_PLANE + o);
            }
        }

        // prefetch next K-tile into the other buffer (DMA, overlaps MFMA below)
        int kn = ks + 1, jn = jt;
        if (kn == 24) { kn = 0; jn = jt + 1; }
        if (jn < 6)
            STAGE4(Abuf[cur ^ 1], Xb + (size_t)(jn * 128 + srow) * HID + kn * 32 + scol);

        if (ks == 0) {
#pragma unroll
            for (int ti = 0; ti < 2; ++ti)
#pragma unroll
                for (int tj = 0; tj < 2; ++tj)
#pragma unroll
                    for (int e = 0; e < 16; ++e) acc[ti][tj][e] = 0.f;
        }

        const float* Ab = Abuf[cur];
#pragma unroll
        for (int ti = 0; ti < 2; ++ti) {
            const int rt = wj * 2 + ti;
#pragma unroll
            for (int kh = 0; kh < 2; ++kh) {
                // A fragment: lane l -> X[row = l&31][k = kh*16 + (l>>5)*8 + 0..7]
                const int fb = ((rt * 2 + kh) * 128 + l5 * 64 + m32) * 4;
                const float4_t x0 = *(const float4_t*)&Ab[fb];         // q=0
                const float4_t x1 = *(const float4_t*)&Ab[fb + 128];   // q=1
                half8 ah, al;
                convert8(x0, x1, ah, al);
#pragma unroll
                for (int tj = 0; tj < 2; ++tj) {
                    acc[ti][tj] = __builtin_amdgcn_mfma_f32_32x32x16_f16(ah, bh[tj][kh], acc[ti][tj], 0, 0, 0);
                    acc[ti][tj] = __builtin_amdgcn_mfma_f32_32x32x16_f16(al, bh[tj][kh], acc[ti][tj], 0, 0, 0);
                    acc[ti][tj] = __builtin_amdgcn_mfma_f32_32x32x16_f16(ah, bl[tj][kh], acc[ti][tj], 0, 0, 0);
                }
            }
        }

        if (ks == 23) {
            // fold P against fp32 op.  C layout (32x32): col i = l&31,
            // row j = (r&3) + 8*(r>>2) + 4*(l>>5)  (+ tile bases)
#pragma unroll
            for (int tj = 0; tj < 2; ++tj) {
                const int i_abs = i0 + wi * 64 + tj * 32 + m32;
                float s = 0.f;
#pragma unroll
                for (int ti = 0; ti < 2; ++ti) {
                    const int jb = j0 + wj * 64 + ti * 32 + l5 * 4;
#pragma unroll
                    for (int r2 = 0; r2 < 4; ++r2) {
                        const float4_t ov = *(const float4_t*)(OP + (size_t)i_abs * HID + jb + r2 * 8);
                        s += acc[ti][tj][r2 * 4 + 0] * ov[0]
                           + acc[ti][tj][r2 * 4 + 1] * ov[1]
                           + acc[ti][tj][r2 * 4 + 2] * ov[2]
                           + acc[ti][tj][r2 * 4 + 3] * ov[3];
                    }
                }
                if (tj == 0) p0 += s; else p1 += s;
            }
        }

        // single barrier per step: drains DMA (vmcnt) + LDS reads, flips buffers
        __syncthreads();
        ks = kn; jt = jn;
    }
#undef STAGE4

    // lanes l and l+32 hold disjoint j-subsets of the same i
    p0 += __shfl_xor(p0, 32);
    p1 += __shfl_xor(p1, 32);
    if (lane < 32) {
        Dred[wj][wi * 64 + lane]      = p0;
        Dred[wj][wi * 64 + 32 + lane] = p1;
    }
    __syncthreads();
    if (tid < 128)
        out[(size_t)b * HID + i0 + tid] = Dred[0][tid] + Dred[1][tid];
}

// in-place row softmax: 128 rows x 768
__global__ __launch_bounds__(768)
void softmax_rows(float* __restrict__ out)
{
    const int row = blockIdx.x;
    const int t = threadIdx.x;
    const int wave = t >> 6, lane = t & 63;
    __shared__ float redm[12];
    __shared__ float reds[12];

    float v = out[(size_t)row * HID + t];

    float m = v;
#pragma unroll
    for (int o = 32; o >= 1; o >>= 1) m = fmaxf(m, __shfl_xor(m, o));
    if (lane == 0) redm[wave] = m;
    __syncthreads();
    if (t == 0) {
        float mm = redm[0];
        for (int w = 1; w < 12; ++w) mm = fmaxf(mm, redm[w]);
        redm[0] = mm;
    }
    __syncthreads();
    m = redm[0];

    const float e = expf(v - m);
    float s = e;
#pragma unroll
    for (int o = 32; o >= 1; o >>= 1) s += __shfl_xor(s, o);
    if (lane == 0) reds[wave] = s;
    __syncthreads();
    if (t == 0) {
        float ss = 0.f;
        for (int w = 0; w < 12; ++w) ss += reds[w];
        reds[0] = ss;
    }
    __syncthreads();
    out[(size_t)row * HID + t] = e / reds[0];
}

extern "C" void kernel_launch(void* const* d_in, const int* in_sizes, int n_in,
                              void* d_out, int out_size, void* d_ws, size_t ws_size,
                              hipStream_t stream)
{
    const float* X  = (const float*)d_in[0];   // [128,768,768] fp32
    const float* OP = (const float*)d_in[1];   // [768,768] fp32
    float* out = (float*)d_out;                // [128,768] fp32
    _Float16* opws = (_Float16*)d_ws;          // 2.36 MB pre-split op

    hipLaunchKernelGGL(split_op, dim3(OP_TILES / 4), dim3(256), 0, stream, OP, opws);
    hipLaunchKernelGGL(diag_quad_kernel, dim3(NB * 6), dim3(256), 0, stream, X, OP, opws, out);
    hipLaunchKernelGGL(softmax_rows, dim3(NB), dim3(768), 0, stream, out);
}